// Round 8
// baseline (841.169 us; speedup 1.0000x reference)
//
#include <hip/hip_runtime.h>

// GraphConv: out[t] += input[s] * (esgn*enorm), 3.2M edges, 100K nodes, D=32 fp32.
// Round 8: accum rewritten edge-per-thread. R7's 8x unroll was re-serialized by
// the compiler (VGPR=20 proves <=2 loads in flight). Now each thread owns an
// edge: 8 independent float4 row loads (structural MLP), 32 LDS atomics with
// rotation swizzle acc[ln*32+((j+ln)&31)] -> bank (j+ln)%32, ~2-way = free.

#define NB   256
#define MAXK 256          // max buckets (span 512 -> supports n_nodes <= 131072)
#define SPAN_SHIFT 9      // bucket span = 512 nodes
#define SPAN 512
#define PT   7680         // partition tile edges (30/thread); srec = 60KB LDS

__global__ __launch_bounds__(NB) void hist_kernel(
    const int* __restrict__ tidx, int* __restrict__ bcnt, int n_edges)
{
    __shared__ int lh[MAXK];
    for (int i = threadIdx.x; i < MAXK; i += NB) lh[i] = 0;
    __syncthreads();
    int stride = gridDim.x * NB;
    for (int e = blockIdx.x * NB + threadIdx.x; e < n_edges; e += stride)
        atomicAdd(&lh[tidx[e] >> SPAN_SHIFT], 1);
    __syncthreads();
    for (int i = threadIdx.x; i < MAXK; i += NB)
        if (lh[i]) atomicAdd(&bcnt[i], lh[i]);
}

__global__ __launch_bounds__(MAXK) void scan_kernel(
    const int* __restrict__ bcnt, int* __restrict__ bbase, int* __restrict__ bcur)
{
    __shared__ int part[MAXK];
    int t = threadIdx.x;
    int c = bcnt[t];
    part[t] = c;
    __syncthreads();
    for (int off = 1; off < MAXK; off <<= 1) {
        int v = (t >= off) ? part[t - off] : 0;
        __syncthreads();
        part[t] += v;
        __syncthreads();
    }
    int excl = part[t] - c;
    bbase[t] = excl;
    bcur[t] = excl;
    if (t == MAXK - 1) bbase[MAXK] = part[MAXK - 1];
}

__global__ __launch_bounds__(NB) void partition_kernel(
    const int* __restrict__ sidx, const int* __restrict__ tidx,
    const float* __restrict__ enorm, const float* __restrict__ esgn,
    int* __restrict__ bcur, int2* __restrict__ recs, int n_edges)
{
    __shared__ int2 srec[PT];              // 60 KB
    __shared__ int lh[MAXK];
    __shared__ int lbase[MAXK];
    __shared__ int lcur[MAXK];
    __shared__ int gb[MAXK];
    int t = threadIdx.x;
    lh[t] = 0;
    __syncthreads();

    size_t tb = (size_t)blockIdx.x * PT;
    for (int j = 0; j < PT / NB; ++j) {
        int e = (int)tb + j * NB + t;
        if (e < n_edges) atomicAdd(&lh[tidx[e] >> SPAN_SHIFT], 1);
    }
    __syncthreads();
    int c = lh[t];
    lbase[t] = c;
    __syncthreads();
    for (int off = 1; off < MAXK; off <<= 1) {
        int v = (t >= off) ? lbase[t - off] : 0;
        __syncthreads();
        lbase[t] += v;
        __syncthreads();
    }
    int excl = lbase[t] - c;
    __syncthreads();
    lbase[t] = excl;
    lcur[t] = excl;
    if (c > 0) gb[t] = atomicAdd(&bcur[t], c);
    __syncthreads();
    for (int j = 0; j < PT / NB; ++j) {
        int e = (int)tb + j * NB + t;
        if (e < n_edges) {
            int tn = tidx[e];
            int b = tn >> SPAN_SHIFT;
            unsigned rec = ((unsigned)sidx[e] << SPAN_SHIFT) | (unsigned)(tn & (SPAN - 1));
            float w = enorm[e] * esgn[e];
            int p = atomicAdd(&lcur[b], 1);
            srec[p] = make_int2((int)rec, __float_as_int(w));
        }
    }
    __syncthreads();
    int cnt = lh[t];
    if (cnt > 0) {
        int lb = lbase[t];
        int g = gb[t];
        for (int i = 0; i < cnt; ++i) recs[g + i] = srec[lb + i];
    }
}

// One block per bucket. Edge-per-thread: each thread loads one rec (coalesced),
// gathers the full 128B input row as 8 independent float4 loads, and does 32
// LDS atomics with in-row rotation swizzle (bank = (j+ln)%32).
__global__ __launch_bounds__(1024) void accum_kernel(
    const float* __restrict__ input, const int2* __restrict__ recs,
    const int* __restrict__ bbase, float* __restrict__ out, int n_nodes)
{
    __shared__ float acc[SPAN * 32];       // 64 KB
    int b = blockIdx.x;
    for (int i = threadIdx.x; i < SPAN * 32; i += 1024) acc[i] = 0.f;
    __syncthreads();
    int beg = bbase[b], end = bbase[b + 1];

    for (int i = beg + threadIdx.x; i < end; i += 1024) {
        int2 r = recs[i];                          // coalesced 8B load
        float w = __int_as_float(r.y);
        unsigned u = (unsigned)r.x;
        int s = (int)(u >> SPAN_SHIFT);
        int ln = (int)(u & (SPAN - 1));
        const float4* row = (const float4*)(input + (size_t)s * 32);
        float4 v[8];
#pragma unroll
        for (int q = 0; q < 8; ++q) v[q] = row[q]; // 8 independent 16B loads
        float* ap = &acc[ln * 32];
#pragma unroll
        for (int q = 0; q < 8; ++q) {
            atomicAdd(&ap[((q * 4 + 0) + ln) & 31], w * v[q].x);
            atomicAdd(&ap[((q * 4 + 1) + ln) & 31], w * v[q].y);
            atomicAdd(&ap[((q * 4 + 2) + ln) & 31], w * v[q].z);
            atomicAdd(&ap[((q * 4 + 3) + ln) & 31], w * v[q].w);
        }
    }
    __syncthreads();
    size_t obase = (size_t)b * SPAN * 32;
    int lim = n_nodes * 32 - (int)obase;
    for (int i = threadIdx.x; i < SPAN * 32; i += 1024) {
        if (i < lim) {
            int ln = i >> 5, j = i & 31;
            out[obase + i] = acc[ln * 32 + ((j + ln) & 31)];  // un-rotate
        }
    }
}

// Fallback (R3): direct atomic scatter, used only if ws/shape checks fail.
__global__ __launch_bounds__(NB) void graphconv_scatter(
    const float* __restrict__ input, const int* __restrict__ sidx,
    const int* __restrict__ tidx, const float* __restrict__ enorm,
    const float* __restrict__ esgn, float* __restrict__ out, int n_edges)
{
    int t = blockIdx.x * NB + threadIdx.x;
    int e = t >> 3;
    int sub = t & 7;
    if (e >= n_edges) return;
    int s = sidx[e];
    int d = tidx[e];
    float w = enorm[e] * esgn[e];
    const float4* src = (const float4*)(input + (size_t)s * 32);
    float4 v = src[sub];
    float* op = out + (size_t)d * 32 + sub * 4;
    atomicAdd(op + 0, v.x * w);
    atomicAdd(op + 1, v.y * w);
    atomicAdd(op + 2, v.z * w);
    atomicAdd(op + 3, v.w * w);
}

extern "C" void kernel_launch(void* const* d_in, const int* in_sizes, int n_in,
                              void* d_out, int out_size, void* d_ws, size_t ws_size,
                              hipStream_t stream) {
    const float* input = (const float*)d_in[0];
    const int*   eidx  = (const int*)d_in[1];   // int64 in reference -> int32 here
    const float* enorm = (const float*)d_in[2];
    const float* esgn  = (const float*)d_in[3];
    float*       out   = (float*)d_out;

    int n_edges = in_sizes[1] / 2;             // eidx is (2, n_edges)
    int n_nodes = in_sizes[0] / 32;            // input is (n_nodes, 32)
    const int* sidx = eidx;
    const int* tidx = eidx + n_edges;

    int K = (n_nodes + SPAN - 1) >> SPAN_SHIFT;

    // Workspace: recs[int2 x n_edges] | bcnt[MAXK] | bcur[MAXK] | bbase[MAXK+1]
    size_t need = (size_t)n_edges * 8 + ((size_t)3 * MAXK + 1) * 4;

    if (ws_size >= need && K <= MAXK && n_nodes <= (MAXK << SPAN_SHIFT)) {
        int2* recs  = (int2*)d_ws;
        int*  bcnt  = (int*)(recs + n_edges);
        int*  bcur  = bcnt + MAXK;
        int*  bbase = bcur + MAXK;

        hipMemsetAsync(bcnt, 0, MAXK * sizeof(int), stream);

        hist_kernel     <<<1024, NB,   0, stream>>>(tidx, bcnt, n_edges);
        scan_kernel     <<<1,    MAXK, 0, stream>>>(bcnt, bbase, bcur);
        int pg = (n_edges + PT - 1) / PT;
        partition_kernel<<<pg,   NB,   0, stream>>>(sidx, tidx, enorm, esgn,
                                                    bcur, recs, n_edges);
        accum_kernel    <<<K,    1024, 0, stream>>>(input, recs, bbase, out,
                                                    n_nodes);
    } else {
        hipMemsetAsync(d_out, 0, (size_t)out_size * sizeof(float), stream);
        size_t threads_total = (size_t)n_edges * 8;
        int grid = (int)((threads_total + NB - 1) / NB);
        graphconv_scatter<<<grid, NB, 0, stream>>>(input, sidx, tidx, enorm, esgn,
                                                   out, n_edges);
    }
}

// Round 9
// 840.870 us; speedup vs baseline: 1.0004x; 1.0004x over previous
//
#include <hip/hip_runtime.h>

// GraphConv: out[t] += input[s] * (esgn*enorm), 3.2M edges, 100K nodes, D=32 fp32.
// Round 9: accum v3 — wave-cooperative. R8 ran at ~5 cache lines in flight per
// CU (Little's law from 226 GB/s @ ~600ns): per-lane row gathers scattered 64
// txns/instr and the compiler serialized batches. Now: 2 rows per instr
// (coalesced, 4 txns), 16-edge batch, sched_barrier(0) fences between
// rec-load / row-load / atomic phases to force loads to stay batched.

#define NB   256
#define MAXK 256          // max buckets (span 512 -> supports n_nodes <= 131072)
#define SPAN_SHIFT 9      // bucket span = 512 nodes
#define SPAN 512
#define PT   7680         // partition tile edges (30/thread); srec = 60KB LDS

__global__ __launch_bounds__(NB) void hist_kernel(
    const int* __restrict__ tidx, int* __restrict__ bcnt, int n_edges)
{
    __shared__ int lh[MAXK];
    for (int i = threadIdx.x; i < MAXK; i += NB) lh[i] = 0;
    __syncthreads();
    int stride = gridDim.x * NB;
    for (int e = blockIdx.x * NB + threadIdx.x; e < n_edges; e += stride)
        atomicAdd(&lh[tidx[e] >> SPAN_SHIFT], 1);
    __syncthreads();
    for (int i = threadIdx.x; i < MAXK; i += NB)
        if (lh[i]) atomicAdd(&bcnt[i], lh[i]);
}

__global__ __launch_bounds__(MAXK) void scan_kernel(
    const int* __restrict__ bcnt, int* __restrict__ bbase, int* __restrict__ bcur)
{
    __shared__ int part[MAXK];
    int t = threadIdx.x;
    int c = bcnt[t];
    part[t] = c;
    __syncthreads();
    for (int off = 1; off < MAXK; off <<= 1) {
        int v = (t >= off) ? part[t - off] : 0;
        __syncthreads();
        part[t] += v;
        __syncthreads();
    }
    int excl = part[t] - c;
    bbase[t] = excl;
    bcur[t] = excl;
    if (t == MAXK - 1) bbase[MAXK] = part[MAXK - 1];
}

__global__ __launch_bounds__(NB) void partition_kernel(
    const int* __restrict__ sidx, const int* __restrict__ tidx,
    const float* __restrict__ enorm, const float* __restrict__ esgn,
    int* __restrict__ bcur, int2* __restrict__ recs, int n_edges)
{
    __shared__ int2 srec[PT];              // 60 KB
    __shared__ int lh[MAXK];
    __shared__ int lbase[MAXK];
    __shared__ int lcur[MAXK];
    __shared__ int gb[MAXK];
    int t = threadIdx.x;
    lh[t] = 0;
    __syncthreads();

    size_t tb = (size_t)blockIdx.x * PT;
    for (int j = 0; j < PT / NB; ++j) {
        int e = (int)tb + j * NB + t;
        if (e < n_edges) atomicAdd(&lh[tidx[e] >> SPAN_SHIFT], 1);
    }
    __syncthreads();
    int c = lh[t];
    lbase[t] = c;
    __syncthreads();
    for (int off = 1; off < MAXK; off <<= 1) {
        int v = (t >= off) ? lbase[t - off] : 0;
        __syncthreads();
        lbase[t] += v;
        __syncthreads();
    }
    int excl = lbase[t] - c;
    __syncthreads();
    lbase[t] = excl;
    lcur[t] = excl;
    if (c > 0) gb[t] = atomicAdd(&bcur[t], c);
    __syncthreads();
    for (int j = 0; j < PT / NB; ++j) {
        int e = (int)tb + j * NB + t;
        if (e < n_edges) {
            int tn = tidx[e];
            int b = tn >> SPAN_SHIFT;
            unsigned rec = ((unsigned)sidx[e] << SPAN_SHIFT) | (unsigned)(tn & (SPAN - 1));
            float w = enorm[e] * esgn[e];
            int p = atomicAdd(&lcur[b], 1);
            srec[p] = make_int2((int)rec, __float_as_int(w));
        }
    }
    __syncthreads();
    int cnt = lh[t];
    if (cnt > 0) {
        int lb = lbase[t];
        int g = gb[t];
        for (int i = 0; i < cnt; ++i) recs[g + i] = srec[lb + i];
    }
}

// One block per bucket. Wave-cooperative accum: instruction q of a 16-edge
// batch covers edges (base+2q, base+2q+1); lanes 0-31 carry row a's 32 floats,
// lanes 32-63 row b's. All loads of a batch are independent; sched_barrier(0)
// fences keep the scheduler from sinking loads into per-edge serial order.
__global__ __launch_bounds__(1024) void accum_kernel(
    const float* __restrict__ input, const int2* __restrict__ recs,
    const int* __restrict__ bbase, float* __restrict__ out, int n_nodes)
{
    __shared__ float acc[SPAN * 32];       // 64 KB
    int b = blockIdx.x;
    for (int i = threadIdx.x; i < SPAN * 32; i += 1024) acc[i] = 0.f;
    __syncthreads();
    int beg = bbase[b], end = bbase[b + 1];

    int lane = threadIdx.x & 63;
    int wave = threadIdx.x >> 6;           // 0..15
    int half = lane >> 5;                  // 0 or 1: which edge of the pair
    int col  = lane & 31;                  // feature index
    const int NW = 16;                     // waves per block

    for (int base = beg + wave * 16; base < end; base += NW * 16) {
        int2 rec[8];
#pragma unroll
        for (int q = 0; q < 8; ++q) {
            int idx = base + 2 * q + half;
            int cidx = idx < end ? idx : end - 1;   // clamped (in-bounds)
            rec[q] = recs[cidx];                    // 2 adjacent addrs/instr
        }
        __builtin_amdgcn_sched_barrier(0);
        float val[8];
        float wgt[8];
        int   ln[8];
#pragma unroll
        for (int q = 0; q < 8; ++q) {
            unsigned u = (unsigned)rec[q].x;
            int s = (int)(u >> SPAN_SHIFT);
            ln[q] = (int)(u & (SPAN - 1));
            wgt[q] = __int_as_float(rec[q].y);
            val[q] = input[(size_t)s * 32 + col];   // coalesced 2-row load
        }
        __builtin_amdgcn_sched_barrier(0);
#pragma unroll
        for (int q = 0; q < 8; ++q) {
            if (base + 2 * q + half < end)
                atomicAdd(&acc[ln[q] * 32 + col], wgt[q] * val[q]);
        }
    }
    __syncthreads();
    size_t obase = (size_t)b * SPAN * 32;
    int lim = n_nodes * 32 - (int)obase;
    for (int i = threadIdx.x; i < SPAN * 32; i += 1024)
        if (i < lim) out[obase + i] = acc[i];
}

// Fallback (R3): direct atomic scatter, used only if ws/shape checks fail.
__global__ __launch_bounds__(NB) void graphconv_scatter(
    const float* __restrict__ input, const int* __restrict__ sidx,
    const int* __restrict__ tidx, const float* __restrict__ enorm,
    const float* __restrict__ esgn, float* __restrict__ out, int n_edges)
{
    int t = blockIdx.x * NB + threadIdx.x;
    int e = t >> 3;
    int sub = t & 7;
    if (e >= n_edges) return;
    int s = sidx[e];
    int d = tidx[e];
    float w = enorm[e] * esgn[e];
    const float4* src = (const float4*)(input + (size_t)s * 32);
    float4 v = src[sub];
    float* op = out + (size_t)d * 32 + sub * 4;
    atomicAdd(op + 0, v.x * w);
    atomicAdd(op + 1, v.y * w);
    atomicAdd(op + 2, v.z * w);
    atomicAdd(op + 3, v.w * w);
}

extern "C" void kernel_launch(void* const* d_in, const int* in_sizes, int n_in,
                              void* d_out, int out_size, void* d_ws, size_t ws_size,
                              hipStream_t stream) {
    const float* input = (const float*)d_in[0];
    const int*   eidx  = (const int*)d_in[1];   // int64 in reference -> int32 here
    const float* enorm = (const float*)d_in[2];
    const float* esgn  = (const float*)d_in[3];
    float*       out   = (float*)d_out;

    int n_edges = in_sizes[1] / 2;             // eidx is (2, n_edges)
    int n_nodes = in_sizes[0] / 32;            // input is (n_nodes, 32)
    const int* sidx = eidx;
    const int* tidx = eidx + n_edges;

    int K = (n_nodes + SPAN - 1) >> SPAN_SHIFT;

    // Workspace: recs[int2 x n_edges] | bcnt[MAXK] | bcur[MAXK] | bbase[MAXK+1]
    size_t need = (size_t)n_edges * 8 + ((size_t)3 * MAXK + 1) * 4;

    if (ws_size >= need && K <= MAXK && n_nodes <= (MAXK << SPAN_SHIFT)) {
        int2* recs  = (int2*)d_ws;
        int*  bcnt  = (int*)(recs + n_edges);
        int*  bcur  = bcnt + MAXK;
        int*  bbase = bcur + MAXK;

        hipMemsetAsync(bcnt, 0, MAXK * sizeof(int), stream);

        hist_kernel     <<<1024, NB,   0, stream>>>(tidx, bcnt, n_edges);
        scan_kernel     <<<1,    MAXK, 0, stream>>>(bcnt, bbase, bcur);
        int pg = (n_edges + PT - 1) / PT;
        partition_kernel<<<pg,   NB,   0, stream>>>(sidx, tidx, enorm, esgn,
                                                    bcur, recs, n_edges);
        accum_kernel    <<<K,    1024, 0, stream>>>(input, recs, bbase, out,
                                                    n_nodes);
    } else {
        hipMemsetAsync(d_out, 0, (size_t)out_size * sizeof(float), stream);
        size_t threads_total = (size_t)n_edges * 8;
        int grid = (int)((threads_total + NB - 1) / NB);
        graphconv_scatter<<<grid, NB, 0, stream>>>(input, sidx, tidx, enorm, esgn,
                                                   out, n_edges);
    }
}

// Round 10
// 371.985 us; speedup vs baseline: 2.2613x; 2.2605x over previous
//
#include <hip/hip_runtime.h>

// GraphConv: out[t] += input[s] * (esgn*enorm), 3.2M edges, 100K nodes, D=32 fp32.
// Round 10: full target-sort, atomic-free accumulate.
//   hist -> 3-phase scan (nodeoff) -> bucket partition (R6, contiguous writes)
//   -> per-bucket node sort (LDS cursors, 130KB write window)
//   -> segmented accum: 8 lanes/node, float4, zero atomics, 12.5K waves.
// R7-R9 lesson: compiler re-serializes batched gathers (VGPR=24 vs needed 40);
// get concurrency from wave count, not ILP.

#define NB   256
#define MAXK 256          // max buckets (span 512 -> n_nodes <= 131072)
#define SPAN_SHIFT 9
#define SPAN 512
#define PT   7680         // partition tile edges; srec = 60KB LDS

__global__ __launch_bounds__(NB) void hist_kernel(
    const int* __restrict__ tidx, int* __restrict__ nodecnt, int n_edges)
{
    int e = blockIdx.x * NB + threadIdx.x;
    if (e < n_edges) atomicAdd(&nodecnt[tidx[e]], 1);
}

__global__ __launch_bounds__(NB) void scan_bsum(
    const int* __restrict__ counts, int* __restrict__ bsum, int n_nodes)
{
    __shared__ int red[NB];
    int gid = blockIdx.x * NB + threadIdx.x;
    red[threadIdx.x] = (gid < n_nodes) ? counts[gid] : 0;
    __syncthreads();
    for (int off = NB / 2; off > 0; off >>= 1) {
        if (threadIdx.x < off) red[threadIdx.x] += red[threadIdx.x + off];
        __syncthreads();
    }
    if (threadIdx.x == 0) bsum[blockIdx.x] = red[0];
}

__global__ __launch_bounds__(1024) void scan_bbase(int* __restrict__ bsum, int nblk)
{
    __shared__ int part[1024];
    int t = threadIdx.x;
    part[t] = (t < nblk) ? bsum[t] : 0;
    __syncthreads();
    for (int off = 1; off < 1024; off <<= 1) {
        int v = (t >= off) ? part[t - off] : 0;
        __syncthreads();
        part[t] += v;
        __syncthreads();
    }
    if (t < nblk) bsum[t] = (t == 0) ? 0 : part[t - 1];
}

__global__ __launch_bounds__(NB) void scan_write(
    const int* __restrict__ counts, const int* __restrict__ bsum,
    int* __restrict__ offsets, int* __restrict__ cursors, int n_nodes)
{
    __shared__ int part[NB];
    int t = threadIdx.x;
    int gid = blockIdx.x * NB + t;
    int c = (gid < n_nodes) ? counts[gid] : 0;
    part[t] = c;
    __syncthreads();
    for (int off = 1; off < NB; off <<= 1) {
        int v = (t >= off) ? part[t - off] : 0;
        __syncthreads();
        part[t] += v;
        __syncthreads();
    }
    int excl = part[t] - c + bsum[blockIdx.x];
    if (gid < n_nodes) {
        offsets[gid] = excl;
        cursors[gid] = excl;
        if (gid == n_nodes - 1) offsets[n_nodes] = excl + c;
    }
}

__global__ __launch_bounds__(NB) void bcur_init(
    const int* __restrict__ nodeoff, int* __restrict__ bcur, int K)
{
    int t = blockIdx.x * NB + threadIdx.x;
    if (t < K) bcur[t] = nodeoff[t << SPAN_SHIFT];
}

// R6 partition (verified): tile-local bucket sort in LDS, contiguous run writes.
__global__ __launch_bounds__(NB) void partition_kernel(
    const int* __restrict__ sidx, const int* __restrict__ tidx,
    const float* __restrict__ enorm, const float* __restrict__ esgn,
    int* __restrict__ bcur, int2* __restrict__ recs, int n_edges)
{
    __shared__ int2 srec[PT];              // 60 KB
    __shared__ int lh[MAXK];
    __shared__ int lbase[MAXK];
    __shared__ int lcur[MAXK];
    __shared__ int gb[MAXK];
    int t = threadIdx.x;
    lh[t] = 0;
    __syncthreads();

    size_t tb = (size_t)blockIdx.x * PT;
    for (int j = 0; j < PT / NB; ++j) {
        int e = (int)tb + j * NB + t;
        if (e < n_edges) atomicAdd(&lh[tidx[e] >> SPAN_SHIFT], 1);
    }
    __syncthreads();
    int c = lh[t];
    lbase[t] = c;
    __syncthreads();
    for (int off = 1; off < MAXK; off <<= 1) {
        int v = (t >= off) ? lbase[t - off] : 0;
        __syncthreads();
        lbase[t] += v;
        __syncthreads();
    }
    int excl = lbase[t] - c;
    __syncthreads();
    lbase[t] = excl;
    lcur[t] = excl;
    if (c > 0) gb[t] = atomicAdd(&bcur[t], c);
    __syncthreads();
    for (int j = 0; j < PT / NB; ++j) {
        int e = (int)tb + j * NB + t;
        if (e < n_edges) {
            int tn = tidx[e];
            int b = tn >> SPAN_SHIFT;
            unsigned rec = ((unsigned)sidx[e] << SPAN_SHIFT) | (unsigned)(tn & (SPAN - 1));
            float w = enorm[e] * esgn[e];
            int p = atomicAdd(&lcur[b], 1);
            srec[p] = make_int2((int)rec, __float_as_int(w));
        }
    }
    __syncthreads();
    int cnt = lh[t];
    if (cnt > 0) {
        int lb = lbase[t];
        int g = gb[t];
        for (int i = 0; i < cnt; ++i) recs[g + i] = srec[lb + i];
    }
}

// Per bucket: LDS per-node cursors (global positions from nodeoff), stream
// bucket recs -> fully node-sorted. Writes confined to a ~130KB window.
__global__ __launch_bounds__(1024) void nodesort_kernel(
    const int2* __restrict__ recs, const int* __restrict__ nodeoff,
    int2* __restrict__ sorted, int n_nodes)
{
    __shared__ int lcur[SPAN];
    int b = blockIdx.x;
    int base_node = b << SPAN_SHIFT;
    for (int i = threadIdx.x; i < SPAN; i += 1024) {
        int node = base_node + i;
        lcur[i] = (node < n_nodes) ? nodeoff[node] : 0;
    }
    __syncthreads();
    int bstart = nodeoff[base_node];
    int lastn = min(base_node + SPAN, n_nodes);
    int bend = nodeoff[lastn];
    for (int i = bstart + threadIdx.x; i < bend; i += 1024) {
        int2 r = recs[i];
        int ln = r.x & (SPAN - 1);
        int pos = atomicAdd(&lcur[ln], 1);
        sorted[pos] = r;
    }
}

// Segmented accumulate: 8 lanes per node, float4 per lane; no atomics.
__global__ __launch_bounds__(NB) void seg_accum(
    const float* __restrict__ input, const int2* __restrict__ sorted,
    const int* __restrict__ nodeoff, float* __restrict__ out, int n_nodes)
{
    int n = blockIdx.x * 32 + (threadIdx.x >> 3);
    int lane = threadIdx.x & 7;
    if (n >= n_nodes) return;
    int beg = nodeoff[n], end = nodeoff[n + 1];
    float4 acc = make_float4(0.f, 0.f, 0.f, 0.f);
    for (int i = beg; i < end; ++i) {
        int2 r = sorted[i];                       // broadcast within group
        float w = __int_as_float(r.y);
        int s = (int)(((unsigned)r.x) >> SPAN_SHIFT);
        float4 v = ((const float4*)(input + (size_t)s * 32))[lane];
        acc.x = fmaf(w, v.x, acc.x);
        acc.y = fmaf(w, v.y, acc.y);
        acc.z = fmaf(w, v.z, acc.z);
        acc.w = fmaf(w, v.w, acc.w);
    }
    ((float4*)(out + (size_t)n * 32))[lane] = acc;
}

// Mid fallback: direct scatter to sorted order via global node cursors.
__global__ __launch_bounds__(NB) void scatter_direct(
    const int* __restrict__ sidx, const int* __restrict__ tidx,
    const float* __restrict__ enorm, const float* __restrict__ esgn,
    int* __restrict__ nodecur, int2* __restrict__ sorted, int n_edges)
{
    int e = blockIdx.x * NB + threadIdx.x;
    if (e >= n_edges) return;
    int tn = tidx[e];
    int pos = atomicAdd(&nodecur[tn], 1);
    unsigned rec = ((unsigned)sidx[e] << SPAN_SHIFT) | (unsigned)(tn & (SPAN - 1));
    sorted[pos] = make_int2((int)rec, __float_as_int(enorm[e] * esgn[e]));
}

// Last-resort fallback (R3): direct atomic scatter.
__global__ __launch_bounds__(NB) void graphconv_scatter(
    const float* __restrict__ input, const int* __restrict__ sidx,
    const int* __restrict__ tidx, const float* __restrict__ enorm,
    const float* __restrict__ esgn, float* __restrict__ out, int n_edges)
{
    int t = blockIdx.x * NB + threadIdx.x;
    int e = t >> 3;
    int sub = t & 7;
    if (e >= n_edges) return;
    int s = sidx[e];
    int d = tidx[e];
    float w = enorm[e] * esgn[e];
    const float4* src = (const float4*)(input + (size_t)s * 32);
    float4 v = src[sub];
    float* op = out + (size_t)d * 32 + sub * 4;
    atomicAdd(op + 0, v.x * w);
    atomicAdd(op + 1, v.y * w);
    atomicAdd(op + 2, v.z * w);
    atomicAdd(op + 3, v.w * w);
}

extern "C" void kernel_launch(void* const* d_in, const int* in_sizes, int n_in,
                              void* d_out, int out_size, void* d_ws, size_t ws_size,
                              hipStream_t stream) {
    const float* input = (const float*)d_in[0];
    const int*   eidx  = (const int*)d_in[1];   // int64 in reference -> int32 here
    const float* enorm = (const float*)d_in[2];
    const float* esgn  = (const float*)d_in[3];
    float*       out   = (float*)d_out;

    int n_edges = in_sizes[1] / 2;             // eidx is (2, n_edges)
    int n_nodes = in_sizes[0] / 32;            // input is (n_nodes, 32)
    const int* sidx = eidx;
    const int* tidx = eidx + n_edges;

    int K    = (n_nodes + SPAN - 1) >> SPAN_SHIFT;   // 196
    int nblk = (n_nodes + NB - 1) / NB;              // 391

    // Full: sorted[E int2] | recs[E int2] | nodecnt[n] | nodeoff[n+1]
    //       | nodecur[n] | bsum[nblk] | bcur[MAXK]
    size_t need_full = (size_t)n_edges * 16 +
                       ((size_t)3 * n_nodes + 1 + nblk + MAXK) * 4;
    // Mid:  sorted[E int2] | nodecnt | nodeoff | nodecur | bsum
    size_t need_mid  = (size_t)n_edges * 8 +
                       ((size_t)3 * n_nodes + 1 + nblk) * 4;

    int eg = (n_edges + NB - 1) / NB;
    int ag = (n_nodes + 31) / 32;

    if (ws_size >= need_full && K <= MAXK && nblk <= 1024) {
        int2* sorted  = (int2*)d_ws;
        int2* recs    = sorted + n_edges;
        int*  nodecnt = (int*)(recs + n_edges);
        int*  nodeoff = nodecnt + n_nodes;
        int*  nodecur = nodeoff + (n_nodes + 1);
        int*  bsum    = nodecur + n_nodes;
        int*  bcur    = bsum + nblk;

        hipMemsetAsync(nodecnt, 0, (size_t)n_nodes * sizeof(int), stream);
        hist_kernel     <<<eg,   NB,   0, stream>>>(tidx, nodecnt, n_edges);
        scan_bsum       <<<nblk, NB,   0, stream>>>(nodecnt, bsum, n_nodes);
        scan_bbase      <<<1,    1024, 0, stream>>>(bsum, nblk);
        scan_write      <<<nblk, NB,   0, stream>>>(nodecnt, bsum, nodeoff,
                                                    nodecur, n_nodes);
        bcur_init       <<<1,    NB,   0, stream>>>(nodeoff, bcur, K);
        int pg = (n_edges + PT - 1) / PT;
        partition_kernel<<<pg,   NB,   0, stream>>>(sidx, tidx, enorm, esgn,
                                                    bcur, recs, n_edges);
        nodesort_kernel <<<K,    1024, 0, stream>>>(recs, nodeoff, sorted,
                                                    n_nodes);
        seg_accum       <<<ag,   NB,   0, stream>>>(input, sorted, nodeoff,
                                                    out, n_nodes);
    } else if (ws_size >= need_mid && nblk <= 1024) {
        int2* sorted  = (int2*)d_ws;
        int*  nodecnt = (int*)(sorted + n_edges);
        int*  nodeoff = nodecnt + n_nodes;
        int*  nodecur = nodeoff + (n_nodes + 1);
        int*  bsum    = nodecur + n_nodes;

        hipMemsetAsync(nodecnt, 0, (size_t)n_nodes * sizeof(int), stream);
        hist_kernel   <<<eg,   NB,   0, stream>>>(tidx, nodecnt, n_edges);
        scan_bsum     <<<nblk, NB,   0, stream>>>(nodecnt, bsum, n_nodes);
        scan_bbase    <<<1,    1024, 0, stream>>>(bsum, nblk);
        scan_write    <<<nblk, NB,   0, stream>>>(nodecnt, bsum, nodeoff,
                                                  nodecur, n_nodes);
        scatter_direct<<<eg,   NB,   0, stream>>>(sidx, tidx, enorm, esgn,
                                                  nodecur, sorted, n_edges);
        seg_accum     <<<ag,   NB,   0, stream>>>(input, sorted, nodeoff,
                                                  out, n_nodes);
    } else {
        hipMemsetAsync(d_out, 0, (size_t)out_size * sizeof(float), stream);
        size_t threads_total = (size_t)n_edges * 8;
        int grid = (int)((threads_total + NB - 1) / NB);
        graphconv_scatter<<<grid, NB, 0, stream>>>(input, sidx, tidx, enorm, esgn,
                                                   out, n_edges);
    }
}

// Round 11
// 278.802 us; speedup vs baseline: 3.0171x; 1.3342x over previous
//
#include <hip/hip_runtime.h>

// GraphConv: out[t] += input[s] * (esgn*enorm), 3.2M edges, 100K nodes, D=32 fp32.
// Round 11: kill the node-level global-atomic histogram (R10: 129us, 99.8MB
// atomic write-through). Bucket hist in LDS + per-bucket fused node-hist/scan/
// scatter (all node counters in LDS). Pipeline:
//   bhist(LDS) -> bscan -> partition (R6, verified) -> nodesort2 (fused) ->
//   seg_accum (atomic-free, 12.5K waves).

#define NB   256
#define MAXK 256          // max buckets (span 512 -> n_nodes <= 131072)
#define SPAN_SHIFT 9
#define SPAN 512
#define PT   7680         // partition tile edges; srec = 60KB LDS

// Bucket-level histogram: LDS counters, one global atomic per bucket/block.
__global__ __launch_bounds__(NB) void bhist_kernel(
    const int* __restrict__ tidx, int* __restrict__ bcnt, int n_edges)
{
    __shared__ int lh[MAXK];
    for (int i = threadIdx.x; i < MAXK; i += NB) lh[i] = 0;
    __syncthreads();
    int stride = gridDim.x * NB;
    for (int e = blockIdx.x * NB + threadIdx.x; e < n_edges; e += stride)
        atomicAdd(&lh[tidx[e] >> SPAN_SHIFT], 1);
    __syncthreads();
    for (int i = threadIdx.x; i < MAXK; i += NB)
        if (lh[i]) atomicAdd(&bcnt[i], lh[i]);
}

// Exclusive scan over MAXK bucket counts -> bbase[0..MAXK], bcur=bbase.
__global__ __launch_bounds__(MAXK) void bscan_kernel(
    const int* __restrict__ bcnt, int* __restrict__ bbase, int* __restrict__ bcur)
{
    __shared__ int part[MAXK];
    int t = threadIdx.x;
    int c = bcnt[t];
    part[t] = c;
    __syncthreads();
    for (int off = 1; off < MAXK; off <<= 1) {
        int v = (t >= off) ? part[t - off] : 0;
        __syncthreads();
        part[t] += v;
        __syncthreads();
    }
    int excl = part[t] - c;
    bbase[t] = excl;
    bcur[t] = excl;
    if (t == MAXK - 1) bbase[MAXK] = part[MAXK - 1];
}

// R6 partition (verified): tile-local bucket sort in LDS, contiguous run writes.
__global__ __launch_bounds__(NB) void partition_kernel(
    const int* __restrict__ sidx, const int* __restrict__ tidx,
    const float* __restrict__ enorm, const float* __restrict__ esgn,
    int* __restrict__ bcur, int2* __restrict__ recs, int n_edges)
{
    __shared__ int2 srec[PT];              // 60 KB
    __shared__ int lh[MAXK];
    __shared__ int lbase[MAXK];
    __shared__ int lcur[MAXK];
    __shared__ int gb[MAXK];
    int t = threadIdx.x;
    lh[t] = 0;
    __syncthreads();

    size_t tb = (size_t)blockIdx.x * PT;
    for (int j = 0; j < PT / NB; ++j) {
        int e = (int)tb + j * NB + t;
        if (e < n_edges) atomicAdd(&lh[tidx[e] >> SPAN_SHIFT], 1);
    }
    __syncthreads();
    int c = lh[t];
    lbase[t] = c;
    __syncthreads();
    for (int off = 1; off < MAXK; off <<= 1) {
        int v = (t >= off) ? lbase[t - off] : 0;
        __syncthreads();
        lbase[t] += v;
        __syncthreads();
    }
    int excl = lbase[t] - c;
    __syncthreads();
    lbase[t] = excl;
    lcur[t] = excl;
    if (c > 0) gb[t] = atomicAdd(&bcur[t], c);
    __syncthreads();
    for (int j = 0; j < PT / NB; ++j) {
        int e = (int)tb + j * NB + t;
        if (e < n_edges) {
            int tn = tidx[e];
            int b = tn >> SPAN_SHIFT;
            unsigned rec = ((unsigned)sidx[e] << SPAN_SHIFT) | (unsigned)(tn & (SPAN - 1));
            float w = enorm[e] * esgn[e];
            int p = atomicAdd(&lcur[b], 1);
            srec[p] = make_int2((int)rec, __float_as_int(w));
        }
    }
    __syncthreads();
    int cnt = lh[t];
    if (cnt > 0) {
        int lb = lbase[t];
        int g = gb[t];
        for (int i = 0; i < cnt; ++i) recs[g + i] = srec[lb + i];
    }
}

// Fused per-bucket node hist + scan + scatter. Bucket recs are L2-hot
// (~130KB); two passes. Writes nodeoff and the node-sorted rec array.
__global__ __launch_bounds__(1024) void nodesort2_kernel(
    const int2* __restrict__ recs, const int* __restrict__ bbase,
    int* __restrict__ nodeoff, int2* __restrict__ sorted, int n_nodes, int K)
{
    __shared__ int lcnt[SPAN];
    __shared__ int lpart[SPAN];
    __shared__ int lcur[SPAN];
    int b = blockIdx.x;
    int t = threadIdx.x;
    int base_node = b << SPAN_SHIFT;
    int bstart = bbase[b], bend = bbase[b + 1];

    for (int i = t; i < SPAN; i += 1024) lcnt[i] = 0;
    __syncthreads();
    // pass A: node histogram for this bucket
    for (int i = bstart + t; i < bend; i += 1024)
        atomicAdd(&lcnt[recs[i].x & (SPAN - 1)], 1);
    __syncthreads();
    // LDS exclusive scan over SPAN=512 (threads 0-511 active; barriers uniform)
    int c = (t < SPAN) ? lcnt[t] : 0;
    if (t < SPAN) lpart[t] = c;
    __syncthreads();
    for (int off = 1; off < SPAN; off <<= 1) {
        int v = (t < SPAN && t >= off) ? lpart[t - off] : 0;
        __syncthreads();
        if (t < SPAN) lpart[t] += v;
        __syncthreads();
    }
    if (t < SPAN) {
        int excl = lpart[t] - c;
        int node = base_node + t;
        int gpos = bstart + excl;
        lcur[t] = gpos;
        if (node < n_nodes) nodeoff[node] = gpos;
    }
    if (b == K - 1 && t == 0) nodeoff[n_nodes] = bend;
    __syncthreads();
    // pass B: scatter to node-sorted order
    for (int i = bstart + t; i < bend; i += 1024) {
        int2 r = recs[i];
        int pos = atomicAdd(&lcur[r.x & (SPAN - 1)], 1);
        sorted[pos] = r;
    }
}

// Segmented accumulate: 8 lanes per node, float4 per lane; no atomics.
__global__ __launch_bounds__(NB) void seg_accum(
    const float* __restrict__ input, const int2* __restrict__ sorted,
    const int* __restrict__ nodeoff, float* __restrict__ out, int n_nodes)
{
    int n = blockIdx.x * 32 + (threadIdx.x >> 3);
    int lane = threadIdx.x & 7;
    if (n >= n_nodes) return;
    int beg = nodeoff[n], end = nodeoff[n + 1];
    float4 acc = make_float4(0.f, 0.f, 0.f, 0.f);
    for (int i = beg; i < end; ++i) {
        int2 r = sorted[i];                       // broadcast within group
        float w = __int_as_float(r.y);
        int s = (int)(((unsigned)r.x) >> SPAN_SHIFT);
        float4 v = ((const float4*)(input + (size_t)s * 32))[lane];
        acc.x = fmaf(w, v.x, acc.x);
        acc.y = fmaf(w, v.y, acc.y);
        acc.z = fmaf(w, v.z, acc.z);
        acc.w = fmaf(w, v.w, acc.w);
    }
    ((float4*)(out + (size_t)n * 32))[lane] = acc;
}

// Last-resort fallback (R3): direct atomic scatter.
__global__ __launch_bounds__(NB) void graphconv_scatter(
    const float* __restrict__ input, const int* __restrict__ sidx,
    const int* __restrict__ tidx, const float* __restrict__ enorm,
    const float* __restrict__ esgn, float* __restrict__ out, int n_edges)
{
    int t = blockIdx.x * NB + threadIdx.x;
    int e = t >> 3;
    int sub = t & 7;
    if (e >= n_edges) return;
    int s = sidx[e];
    int d = tidx[e];
    float w = enorm[e] * esgn[e];
    const float4* src = (const float4*)(input + (size_t)s * 32);
    float4 v = src[sub];
    float* op = out + (size_t)d * 32 + sub * 4;
    atomicAdd(op + 0, v.x * w);
    atomicAdd(op + 1, v.y * w);
    atomicAdd(op + 2, v.z * w);
    atomicAdd(op + 3, v.w * w);
}

extern "C" void kernel_launch(void* const* d_in, const int* in_sizes, int n_in,
                              void* d_out, int out_size, void* d_ws, size_t ws_size,
                              hipStream_t stream) {
    const float* input = (const float*)d_in[0];
    const int*   eidx  = (const int*)d_in[1];   // int64 in reference -> int32 here
    const float* enorm = (const float*)d_in[2];
    const float* esgn  = (const float*)d_in[3];
    float*       out   = (float*)d_out;

    int n_edges = in_sizes[1] / 2;             // eidx is (2, n_edges)
    int n_nodes = in_sizes[0] / 32;            // input is (n_nodes, 32)
    const int* sidx = eidx;
    const int* tidx = eidx + n_edges;

    int K = (n_nodes + SPAN - 1) >> SPAN_SHIFT;   // 196

    // Workspace: sorted[E int2] | recs[E int2] | nodeoff[n+1]
    //            | bcnt[MAXK] | bbase[MAXK+1] | bcur[MAXK]
    size_t need = (size_t)n_edges * 16 +
                  ((size_t)n_nodes + 1 + 3 * MAXK + 1) * 4;

    if (ws_size >= need && K <= MAXK) {
        int2* sorted  = (int2*)d_ws;
        int2* recs    = sorted + n_edges;
        int*  nodeoff = (int*)(recs + n_edges);
        int*  bcnt    = nodeoff + (n_nodes + 1);
        int*  bbase   = bcnt + MAXK;
        int*  bcur    = bbase + (MAXK + 1);

        hipMemsetAsync(bcnt, 0, MAXK * sizeof(int), stream);

        bhist_kernel    <<<1024, NB,   0, stream>>>(tidx, bcnt, n_edges);
        bscan_kernel    <<<1,    MAXK, 0, stream>>>(bcnt, bbase, bcur);
        int pg = (n_edges + PT - 1) / PT;
        partition_kernel<<<pg,   NB,   0, stream>>>(sidx, tidx, enorm, esgn,
                                                    bcur, recs, n_edges);
        nodesort2_kernel<<<K,    1024, 0, stream>>>(recs, bbase, nodeoff,
                                                    sorted, n_nodes, K);
        int ag = (n_nodes + 31) / 32;
        seg_accum       <<<ag,   NB,   0, stream>>>(input, sorted, nodeoff,
                                                    out, n_nodes);
    } else {
        hipMemsetAsync(d_out, 0, (size_t)out_size * sizeof(float), stream);
        size_t threads_total = (size_t)n_edges * 8;
        int grid = (int)((threads_total + NB - 1) / NB);
        graphconv_scatter<<<grid, NB, 0, stream>>>(input, sidx, tidx, enorm, esgn,
                                                   out, n_edges);
    }
}